// Round 4
// baseline (478.623 us; speedup 1.0000x reference)
//
#include <hip/hip_runtime.h>

// Swin-style double-window attention, MI355X. bf16-MFMA GEMMs + MFMA attention.
// B=32, C=256, H=W=64, WS=8, SHIFT=4, HEADS=8, DK=32, L=64, NW=64.
//
// Layouts (per (window,head), 2048 elems bf16):
//   Qt, Kt : [l 64][c 32]  (transposed; MFMA QK contracts over c)
//   V      : [c 32][l 64]  (MFMA PV contracts over s=l)
// Pipeline per chunk of cb batches:
//   x2b  : x fp32 -> bf16
//   A    : QKV GEMM via mfma_f32_16x16x32_bf16; epilogue: bias, Q*=DK^-0.5,
//          -SHIFT channel-half roll, window scatter into Qt/Kt/V layouts
//   attn : per (window,head) MFMA attention (QK^T, in-register softmax, PV),
//          writes Y bf16 [ch][h][w]
//   C    : proj GEMM with +SHIFT channel-half gather

typedef __attribute__((ext_vector_type(8))) short bf16x8;
typedef __attribute__((ext_vector_type(4))) float f32x4;

__device__ __forceinline__ ushort f2bf(float f) {
  uint u = __float_as_uint(f);
  return (ushort)((u + 0x7fffu + ((u >> 16) & 1u)) >> 16);
}

// ------------------------------------------------------------- converters
__global__ __launch_bounds__(256) void x2b_kernel(const float* __restrict__ in,
                                                  ushort* __restrict__ out) {
  const size_t i = ((size_t)blockIdx.x * 256 + threadIdx.x) * 4;
  const float4 f = *reinterpret_cast<const float4*>(in + i);
  ushort4 u;
  u.x = f2bf(f.x); u.y = f2bf(f.y); u.z = f2bf(f.z); u.w = f2bf(f.w);
  *reinterpret_cast<ushort4*>(out + i) = u;
}

__global__ __launch_bounds__(256) void w2b_kernel(const float* __restrict__ wq,
                                                  const float* __restrict__ wkv,
                                                  const float* __restrict__ wproj,
                                                  ushort* __restrict__ Wb) {
  const int i = (blockIdx.x * 256 + threadIdx.x) * 4;
  const int row = i >> 8;
  const float* src = (row < 256) ? (wq + i)
                   : (row < 768) ? (wkv + (i - 65536))
                                 : (wproj + (i - 196608));
  const float4 f = *reinterpret_cast<const float4*>(src);
  ushort4 u;
  u.x = f2bf(f.x); u.y = f2bf(f.y); u.z = f2bf(f.z); u.w = f2bf(f.w);
  *reinterpret_cast<ushort4*>(Wb + i) = u;
}

// ------------------------------------------------------------- kernel A
// D[oc][pix] = sum_c W[oc][c] * X[c][pix].  Tile 128oc x 128pix, K=256, BK=64.
__global__ __launch_bounds__(256) void qkv_mfma_kernel(
    const ushort* __restrict__ xb, const ushort* __restrict__ Wb,
    const float* __restrict__ bq, const float* __restrict__ bkv,
    ushort* __restrict__ Qb, ushort* __restrict__ Kb, ushort* __restrict__ Vb) {
  const int ot = blockIdx.x;       // 0..5 -> out-ch [ot*128, ot*128+128)
  const int pt = blockIdx.y & 31;  // pixel tile within image
  const int lb = blockIdx.y >> 5;  // chunk-local batch
  const int pix0 = pt * 128;

  __shared__ __align__(16) ushort lds[2][2][8192];  // [buf][0=W,1=X][128*64]

  const int tid = threadIdx.x;
  const int l = tid & 63, wv = tid >> 6;
  const int wr = wv >> 1, wc = wv & 1;  // 2x2 wave grid, 64x64 each
  const int pg = tid & 31, cg = tid >> 5;  // X staging
  const int kg = tid & 7, ocr = tid >> 3;  // W staging
  const int l15 = l & 15, l4 = l >> 4;

  const ushort* Wsrc = Wb + (size_t)(ot * 128) * 256;
  const ushort* Xsrc = xb + ((size_t)lb << 20) + pix0;

  ushort4 xr[8];
  bf16x8 wreg[4];
  f32x4 acc[4][4] = {};

#define LOAD_REGS(KK)                                                         \
  {                                                                           \
    const int c0 = (KK) * 64;                                                 \
    _Pragma("unroll") for (int i = 0; i < 8; i++)                             \
        xr[i] = *reinterpret_cast<const ushort4*>(                            \
            Xsrc + ((size_t)(c0 + cg * 8 + i) << 12) + pg * 4);               \
    _Pragma("unroll") for (int ii = 0; ii < 4; ii++)                          \
        wreg[ii] = *reinterpret_cast<const bf16x8*>(                          \
            Wsrc + (size_t)(ocr + 32 * ii) * 256 + c0 + kg * 8);              \
  }

#define WRITE_LDS(BUF)                                                        \
  {                                                                           \
    ushort* Wt = &lds[(BUF)][0][0];                                           \
    ushort* Xt = &lds[(BUF)][1][0];                                           \
    _Pragma("unroll") for (int ii = 0; ii < 4; ii++) {                        \
      const int row = ocr + 32 * ii;                                          \
      *reinterpret_cast<bf16x8*>((char*)Wt + row * 128 +                      \
                                 ((kg * 16) ^ ((row & 7) << 4))) = wreg[ii];  \
    }                                                                         \
    _Pragma("unroll") for (int j = 0; j < 4; j++) {                           \
      const int row = pg * 4 + j;                                             \
      bf16x8 v;                                                               \
      _Pragma("unroll") for (int i = 0; i < 8; i++) {                         \
        const ushort e = (j == 0) ? xr[i].x                                   \
                       : (j == 1) ? xr[i].y                                   \
                       : (j == 2) ? xr[i].z : xr[i].w;                        \
        v[i] = (short)e;                                                      \
      }                                                                       \
      *reinterpret_cast<bf16x8*>((char*)Xt + row * 128 +                      \
                                 ((cg * 16) ^ ((row & 7) << 4))) = v;         \
    }                                                                         \
  }

  LOAD_REGS(0)
  WRITE_LDS(0)
  __syncthreads();

#pragma unroll
  for (int kk = 0; kk < 4; kk++) {
    if (kk < 3) LOAD_REGS(kk + 1)
    const ushort* Wt = &lds[kk & 1][0][0];
    const ushort* Xt = &lds[kk & 1][1][0];
#pragma unroll
    for (int ks = 0; ks < 2; ks++) {
      bf16x8 a[4], b[4];
      const int colB = ks * 64 + (l4 << 4);
#pragma unroll
      for (int m = 0; m < 4; m++) {
        const int row = wr * 64 + m * 16 + l15;
        a[m] = *reinterpret_cast<const bf16x8*>(
            (const char*)Wt + row * 128 + (colB ^ ((row & 7) << 4)));
      }
#pragma unroll
      for (int n = 0; n < 4; n++) {
        const int row = wc * 64 + n * 16 + l15;
        b[n] = *reinterpret_cast<const bf16x8*>(
            (const char*)Xt + row * 128 + (colB ^ ((row & 7) << 4)));
      }
#pragma unroll
      for (int m = 0; m < 4; m++)
#pragma unroll
        for (int n = 0; n < 4; n++)
          acc[m][n] = __builtin_amdgcn_mfma_f32_16x16x32_bf16(a[m], b[n],
                                                              acc[m][n], 0, 0, 0);
    }
    if (kk < 3) {
      WRITE_LDS((kk + 1) & 1)
      __syncthreads();
    }
  }

  // epilogue: bias, Q-scale, shift(-4) on second channel half, window scatter
  const float scale = 0.17677669529663687f;  // 32^-0.5
  const int mode = ot >> 1;  // 0=Q 1=K 2=V (uniform per block)
#pragma unroll
  for (int m = 0; m < 4; m++) {
    const int ob = ot * 128 + wr * 64 + m * 16 + (l4 << 2);  // o for r=0
    const int ch = ob & 255;
    const int head = (ch >> 5) & 7;
    const int c0 = ch & 31;
    const bool sh = (ch & 128) != 0;
    float bias[4];
#pragma unroll
    for (int r = 0; r < 4; r++)
      bias[r] = (mode == 0) ? bq[ob + r] : bkv[ob + r - 256];
#pragma unroll
    for (int n = 0; n < 4; n++) {
      const int P = pix0 + wc * 64 + n * 16 + l15;
      const int h = P >> 6, w = P & 63;
      int hh = h, ww2 = w;
      if (sh) { hh = (h + 60) & 63; ww2 = (w + 60) & 63; }
      const int wi = ((hh >> 3) << 3) + (ww2 >> 3);
      const int l2 = ((hh & 7) << 3) + (ww2 & 7);
      const size_t base = ((size_t)(lb * 64 + wi) * 8 + head) << 11;
      if (mode == 2) {
        // V [c][l]: 4 scalar bf16 stores
#pragma unroll
        for (int r = 0; r < 4; r++)
          Vb[base + (size_t)(c0 + r) * 64 + l2] = f2bf(acc[m][n][r] + bias[r]);
      } else {
        // Qt/Kt [l][c]: consecutive c -> one ushort4 store
        ushort4 pk;
        float v0 = acc[m][n][0] + bias[0], v1 = acc[m][n][1] + bias[1];
        float v2 = acc[m][n][2] + bias[2], v3 = acc[m][n][3] + bias[3];
        if (mode == 0) { v0 *= scale; v1 *= scale; v2 *= scale; v3 *= scale; }
        pk.x = f2bf(v0); pk.y = f2bf(v1); pk.z = f2bf(v2); pk.w = f2bf(v3);
        ushort* qk = (mode == 0) ? Qb : Kb;
        *reinterpret_cast<ushort4*>(qk + base + (l2 << 5) + c0) = pk;
      }
    }
  }
#undef LOAD_REGS
#undef WRITE_LDS
}

// ------------------------------------------------------------- kernel B
// Per (window,head) MFMA attention. 4 waves, each owns 16 rows t.
__global__ __launch_bounds__(256) void attn_kernel(
    const ushort* __restrict__ Qb, const ushort* __restrict__ Kb,
    const ushort* __restrict__ Vb, const float* __restrict__ rpb,
    ushort* __restrict__ Y) {
  const int bwh = blockIdx.x;  // (lb*64 + wi)*8 + head
  const int head = bwh & 7;
  const int bw = bwh >> 3;
  const int wi = bw & 63;
  const int lb = bw >> 6;
  const int wh = wi >> 3, ww = wi & 7;

  __shared__ __align__(16) ushort Qs[2048];  // Qt [l][c] swz; reused: Ybuf [c][t]
  __shared__ __align__(16) ushort Ks[2048];  // Kt [l][c] swz
  __shared__ __align__(16) ushort Vs[2048];  // V  [c][l] swz
  __shared__ __align__(16) ushort Ps[4096];  // P  [t][s] bf16 swz
  __shared__ float Rs[232];                  // rpb slice for this head

  const int tid = threadIdx.x;
  const size_t gbase = (size_t)bwh << 11;

  {  // stage Qt, Kt (rows 64B, 4 chunks), V (rows 128B, 8 chunks), rpb
    const int lq = tid >> 2, cq = tid & 3;
    const uint4 qv = *reinterpret_cast<const uint4*>(Qb + gbase + lq * 32 + cq * 8);
    const uint4 kv = *reinterpret_cast<const uint4*>(Kb + gbase + lq * 32 + cq * 8);
    *reinterpret_cast<uint4*>((char*)Qs + lq * 64 + ((cq * 16) ^ ((lq & 3) << 4))) = qv;
    *reinterpret_cast<uint4*>((char*)Ks + lq * 64 + ((cq * 16) ^ ((lq & 3) << 4))) = kv;
    const int cv = tid >> 3, s8 = tid & 7;
    const uint4 vv = *reinterpret_cast<const uint4*>(Vb + gbase + cv * 64 + s8 * 8);
    *reinterpret_cast<uint4*>((char*)Vs + cv * 128 + ((s8 * 16) ^ ((cv & 7) << 4))) = vv;
    if (tid < 225) Rs[tid] = rpb[tid * 8 + head];
  }
  __syncthreads();

  const int l = tid & 63, wv = tid >> 6;
  const int t0 = wv * 16;
  const int l15 = l & 15, l4 = l >> 4;

  // ---- QK^T: S[t][s], t in [t0,t0+16), s in [0,64)
  f32x4 accQ[4] = {};
  {
    const int tr = t0 + l15;
    const bf16x8 af = *reinterpret_cast<const bf16x8*>(
        (const char*)Qs + tr * 64 + ((l4 * 16) ^ ((tr & 3) << 4)));
#pragma unroll
    for (int nt = 0; nt < 4; nt++) {
      const int s = nt * 16 + l15;
      const bf16x8 bfv = *reinterpret_cast<const bf16x8*>(
          (const char*)Ks + s * 64 + ((l4 * 16) ^ ((s & 3) << 4)));
      accQ[nt] = __builtin_amdgcn_mfma_f32_16x16x32_bf16(af, bfv, accQ[nt], 0, 0, 0);
    }
  }

  // ---- bias + shift-mask (D-frag: col s = nt*16+l15, row t = t0+l4*4+r)
#pragma unroll
  for (int nt = 0; nt < 4; nt++) {
    const int s = nt * 16 + l15;
    const int si = s >> 3, sj = s & 7;
    const int hs = wh * 8 + si, wsx = ww * 8 + sj;
    const int cls = (hs < 56 ? 0 : (hs < 60 ? 1 : 2)) * 3 +
                    (wsx < 56 ? 0 : (wsx < 60 ? 1 : 2));
#pragma unroll
    for (int r = 0; r < 4; r++) {
      const int t = t0 + l4 * 4 + r;
      const int ri = t >> 3, rj = t & 7;
      const int hr = wh * 8 + ri, wrx = ww * 8 + rj;
      const int clr = (hr < 56 ? 0 : (hr < 60 ? 1 : 2)) * 3 +
                      (wrx < 56 ? 0 : (wrx < 60 ? 1 : 2));
      float add = Rs[(ri - si + 7) * 15 + (rj - sj + 7)];
      if (clr != cls) add -= 100.f;
      accQ[nt][r] += add;
    }
  }

  // ---- softmax per row t (s spread over 4 regs x 16 lanes of same l4 group)
#pragma unroll
  for (int r = 0; r < 4; r++) {
    float mx = fmaxf(fmaxf(accQ[0][r], accQ[1][r]), fmaxf(accQ[2][r], accQ[3][r]));
#pragma unroll
    for (int off = 1; off < 16; off <<= 1) mx = fmaxf(mx, __shfl_xor(mx, off));
    float e0 = __expf(accQ[0][r] - mx), e1 = __expf(accQ[1][r] - mx);
    float e2 = __expf(accQ[2][r] - mx), e3 = __expf(accQ[3][r] - mx);
    float sm = (e0 + e1) + (e2 + e3);
#pragma unroll
    for (int off = 1; off < 16; off <<= 1) sm += __shfl_xor(sm, off);
    const float rinv = 1.0f / sm;
    const int t = t0 + l4 * 4 + r;
    const int swz = (t & 7) << 4;
    *(ushort*)((char*)Ps + t * 128 + (((0 * 16 + l15) * 2) ^ swz)) = f2bf(e0 * rinv);
    *(ushort*)((char*)Ps + t * 128 + (((1 * 16 + l15) * 2) ^ swz)) = f2bf(e1 * rinv);
    *(ushort*)((char*)Ps + t * 128 + (((2 * 16 + l15) * 2) ^ swz)) = f2bf(e2 * rinv);
    *(ushort*)((char*)Ps + t * 128 + (((3 * 16 + l15) * 2) ^ swz)) = f2bf(e3 * rinv);
  }

  // ---- PV: D2[c][t] = sum_s V[c][s] P[t][s]; wave's own t-block only
  f32x4 acc2[2] = {};
#pragma unroll
  for (int kk = 0; kk < 2; kk++) {
    const int colb = kk * 64 + l4 * 16;  // byte col = s*2
    const int tr = t0 + l15;
    const bf16x8 b2 = *reinterpret_cast<const bf16x8*>(
        (const char*)Ps + tr * 128 + (colb ^ ((tr & 7) << 4)));
#pragma unroll
    for (int mt = 0; mt < 2; mt++) {
      const int c = mt * 16 + l15;
      const bf16x8 a2 = *reinterpret_cast<const bf16x8*>(
          (const char*)Vs + c * 128 + (colb ^ ((c & 7) << 4)));
      acc2[mt] = __builtin_amdgcn_mfma_f32_16x16x32_bf16(a2, b2, acc2[mt], 0, 0, 0);
    }
  }

  __syncthreads();  // all QK reads of Qs done -> safe to reuse as Ybuf

  // Ybuf (=Qs) [c 32][t 64] bf16 swz: lane holds c = mt*16+l4*4+r, t = t0+l15
#pragma unroll
  for (int mt = 0; mt < 2; mt++)
#pragma unroll
    for (int r = 0; r < 4; r++) {
      const int c = mt * 16 + l4 * 4 + r;
      const int t = t0 + l15;
      *(ushort*)((char*)Qs + c * 128 + ((t * 2) ^ ((c & 7) << 4))) =
          f2bf(acc2[mt][r]);
    }
  __syncthreads();

  // coalesced copy-out: one window row (8 pixels = 16B) per thread
  {
    const int c = tid >> 3, chunk = tid & 7;
    const uint4 v = *reinterpret_cast<const uint4*>(
        (const char*)Qs + c * 128 + ((chunk * 16) ^ ((c & 7) << 4)));
    const int ch = head * 32 + c;
    const int hh = wh * 8 + chunk;
    *reinterpret_cast<uint4*>(Y + (((size_t)lb * 256 + ch) << 12) + hh * 64 +
                              ww * 8) = v;
  }
}

// ------------------------------------------------------------- kernel C
__global__ __launch_bounds__(256) void proj_mfma_kernel(
    const ushort* __restrict__ Yb, const ushort* __restrict__ Wb,
    const float* __restrict__ bproj, float* __restrict__ out, int b0) {
  const int ot = blockIdx.x;       // 0..1
  const int pt = blockIdx.y & 31;
  const int lb = blockIdx.y >> 5;
  const int pix0 = pt * 128;

  __shared__ __align__(16) ushort lds[2][2][8192];

  const int tid = threadIdx.x;
  const int l = tid & 63, wv = tid >> 6;
  const int wr = wv >> 1, wc = wv & 1;
  const int pg = tid & 31, cg = tid >> 5;
  const int kg = tid & 7, ocr = tid >> 3;
  const int l15 = l & 15, l4 = l >> 4;

  const ushort* Wsrc = Wb + (size_t)(768 + ot * 128) * 256;
  const ushort* Ysrc = Yb + ((size_t)lb << 20);

  const int P0 = pix0 + pg * 4;
  const int h0 = P0 >> 6, w0 = P0 & 63;
  const int Psh = ((h0 + 60) & 63) * 64 + ((w0 + 60) & 63);

  ushort4 xr[8];
  bf16x8 wreg[4];
  f32x4 acc[4][4] = {};

#define LOAD_REGS_C(KK)                                                       \
  {                                                                           \
    const int c0 = (KK) * 64;                                                 \
    const int srcP = (c0 & 128) ? Psh : P0;                                   \
    _Pragma("unroll") for (int i = 0; i < 8; i++)                             \
        xr[i] = *reinterpret_cast<const ushort4*>(                            \
            Ysrc + ((size_t)(c0 + cg * 8 + i) << 12) + srcP);                 \
    _Pragma("unroll") for (int ii = 0; ii < 4; ii++)                          \
        wreg[ii] = *reinterpret_cast<const bf16x8*>(                          \
            Wsrc + (size_t)(ocr + 32 * ii) * 256 + c0 + kg * 8);              \
  }

#define WRITE_LDS_C(BUF)                                                      \
  {                                                                           \
    ushort* Wt = &lds[(BUF)][0][0];                                           \
    ushort* Xt = &lds[(BUF)][1][0];                                           \
    _Pragma("unroll") for (int ii = 0; ii < 4; ii++) {                        \
      const int row = ocr + 32 * ii;                                          \
      *reinterpret_cast<bf16x8*>((char*)Wt + row * 128 +                      \
                                 ((kg * 16) ^ ((row & 7) << 4))) = wreg[ii];  \
    }                                                                         \
    _Pragma("unroll") for (int j = 0; j < 4; j++) {                           \
      const int row = pg * 4 + j;                                             \
      bf16x8 v;                                                               \
      _Pragma("unroll") for (int i = 0; i < 8; i++) {                         \
        const ushort e = (j == 0) ? xr[i].x                                   \
                       : (j == 1) ? xr[i].y                                   \
                       : (j == 2) ? xr[i].z : xr[i].w;                        \
        v[i] = (short)e;                                                      \
      }                                                                       \
      *reinterpret_cast<bf16x8*>((char*)Xt + row * 128 +                      \
                                 ((cg * 16) ^ ((row & 7) << 4))) = v;         \
    }                                                                         \
  }

  LOAD_REGS_C(0)
  WRITE_LDS_C(0)
  __syncthreads();

#pragma unroll
  for (int kk = 0; kk < 4; kk++) {
    if (kk < 3) LOAD_REGS_C(kk + 1)
    const ushort* Wt = &lds[kk & 1][0][0];
    const ushort* Xt = &lds[kk & 1][1][0];
#pragma unroll
    for (int ks = 0; ks < 2; ks++) {
      bf16x8 a[4], b[4];
      const int colB = ks * 64 + (l4 << 4);
#pragma unroll
      for (int m = 0; m < 4; m++) {
        const int row = wr * 64 + m * 16 + l15;
        a[m] = *reinterpret_cast<const bf16x8*>(
            (const char*)Wt + row * 128 + (colB ^ ((row & 7) << 4)));
      }
#pragma unroll
      for (int n = 0; n < 4; n++) {
        const int row = wc * 64 + n * 16 + l15;
        b[n] = *reinterpret_cast<const bf16x8*>(
            (const char*)Xt + row * 128 + (colB ^ ((row & 7) << 4)));
      }
#pragma unroll
      for (int m = 0; m < 4; m++)
#pragma unroll
        for (int n = 0; n < 4; n++)
          acc[m][n] = __builtin_amdgcn_mfma_f32_16x16x32_bf16(a[m], b[n],
                                                              acc[m][n], 0, 0, 0);
    }
    if (kk < 3) {
      WRITE_LDS_C((kk + 1) & 1)
      __syncthreads();
    }
  }

  const int b = b0 + lb;
#pragma unroll
  for (int m = 0; m < 4; m++) {
#pragma unroll
    for (int r = 0; r < 4; r++) {
      const int o = ot * 128 + wr * 64 + m * 16 + (l4 << 2) + r;
      const float bias = bproj[o];
#pragma unroll
      for (int n = 0; n < 4; n++) {
        const int P = pix0 + wc * 64 + n * 16 + l15;
        out[(((size_t)b * 256 + o) << 12) + P] = acc[m][n][r] + bias;
      }
    }
  }
#undef LOAD_REGS_C
#undef WRITE_LDS_C
}

// ------------------------------------------------------------- launcher
extern "C" void kernel_launch(void* const* d_in, const int* in_sizes, int n_in,
                              void* d_out, int out_size, void* d_ws,
                              size_t ws_size, hipStream_t stream) {
  const float* x = (const float*)d_in[0];
  const float* wq = (const float*)d_in[1];
  const float* bq = (const float*)d_in[2];
  const float* wkv = (const float*)d_in[3];
  const float* bkv = (const float*)d_in[4];
  const float* wproj = (const float*)d_in[5];
  const float* bproj = (const float*)d_in[6];
  const float* rpb = (const float*)d_in[7];
  float* out = (float*)d_out;

  const size_t perB = 1048576ull;                  // 256*4096 elems per batch
  const size_t wbBytes = 1024ull * 256ull * 2ull;  // 512 KB bf16 weights
  const size_t perBatchBytes = 5ull * perB * 2ull; // xb,Q,K,V,Y bf16 = 10 MB

  int chunk = (int)((ws_size > wbBytes ? ws_size - wbBytes : 0) / perBatchBytes);
  if (chunk > 32) chunk = 32;
  if (chunk < 1) chunk = 1;

  char* p = (char*)d_ws;
  ushort* Wb = (ushort*)p; p += wbBytes;
  ushort* xb = (ushort*)p; p += (size_t)chunk * perB * 2;
  ushort* Qb = (ushort*)p; p += (size_t)chunk * perB * 2;
  ushort* Kb = (ushort*)p; p += (size_t)chunk * perB * 2;
  ushort* Vb = (ushort*)p; p += (size_t)chunk * perB * 2;
  ushort* Yb = (ushort*)p;

  w2b_kernel<<<256, 256, 0, stream>>>(wq, wkv, wproj, Wb);

  for (int b0 = 0; b0 < 32; b0 += chunk) {
    const int cb = (32 - b0 < chunk) ? (32 - b0) : chunk;
    x2b_kernel<<<cb * 1024, 256, 0, stream>>>(x + (size_t)b0 * perB, xb);
    qkv_mfma_kernel<<<dim3(6, cb * 32), 256, 0, stream>>>(xb, Wb, bq, bkv,
                                                          Qb, Kb, Vb);
    attn_kernel<<<cb * 512, 256, 0, stream>>>(Qb, Kb, Vb, rpb, Yb);
    proj_mfma_kernel<<<dim3(2, cb * 32), 256, 0, stream>>>(Yb, Wb, bproj,
                                                           out, b0);
  }
}